// Round 3
// baseline (327.419 us; speedup 1.0000x reference)
//
#include <hip/hip_runtime.h>
#include <stdint.h>

#define NUM_BONES  50
#define FEAT       150
#define W          2                          // frames per wave-tile
#define TILE_F     (W * FEAT)                 // 300 floats per tensor per tile
#define THREADS    256
#define WPB        (THREADS / 64)             // 4 waves/block
#define GRID_BLOCKS 1024                      // 4 blocks/CU (LDS 38.4KB)
#define NWAVES     (GRID_BLOCKS * WPB)        // 4096
#define TOTAL_FRAMES (64 * 4096)
#define TOTAL_TILES  (TOTAL_FRAMES / W)       // 131072
#define TPW        (TOTAL_TILES / NWAVES)     // 32 tiles per wave
#define DEPTH      4                          // per-wave ring: 3 tiles in flight
#define NTASK      (W * NUM_BONES)            // 100 bone-tasks per tile

// 50-bone skeleton (body + two 21-bone hands + pad bone (0,2))
__device__ __constant__ int c_ba[NUM_BONES] = {
    0, 1, 2, 3, 1, 5, 6,
    7, 8, 9, 10, 11, 8, 13, 14, 15, 8, 17, 18, 19,
    8, 21, 22, 23, 8, 25, 26, 27,
    4, 29, 30, 31, 32, 29, 34, 35, 36, 29, 38, 39, 40,
    29, 42, 43, 44, 29, 46, 47, 48,
    0
};
__device__ __constant__ int c_bb[NUM_BONES] = {
    1, 2, 3, 4, 5, 6, 7,
    8, 9, 10, 11, 12, 13, 14, 15, 16, 17, 18, 19, 20,
    21, 22, 23, 24, 25, 26, 27, 28,
    29, 30, 31, 32, 33, 34, 35, 36, 37, 38, 39, 40, 41,
    42, 43, 44, 45, 46, 47, 48, 49,
    2
};

#define AS1 __attribute__((address_space(1)))
#define AS3 __attribute__((address_space(3)))

// DMA one float4 per active lane: global (per-lane addr) -> LDS (wave-uniform
// base + lane*16).
__device__ __forceinline__ void gload16(const float* g, float* l)
{
    __builtin_amdgcn_global_load_lds((AS1 unsigned int*)(uintptr_t)g,
                                     (AS3 unsigned int*)(uintptr_t)l,
                                     16, 0, 0);
}

// Stage one tile-pair (preds+targets, 300 floats each) into this wave's slot.
// 4 vmcnt events per wave per tile: 2 full issues (64 lanes, f4 0..63) +
// 2 tail issues (lanes 0..10, f4 64..74). Every wave takes the tail branch.
__device__ __forceinline__ void stage_pair(const float* __restrict__ preds,
                                           const float* __restrict__ targets,
                                           float* slotP, float* slotT,
                                           int ln, long long tile)
{
    const float* p = preds   + tile * TILE_F;
    const float* t = targets + tile * TILE_F;
    gload16(p + (ln << 2), slotP);
    gload16(t + (ln << 2), slotT);
    if (ln < 11) {
        gload16(p + ((64 + ln) << 2), slotP + 256);
        gload16(t + ((64 + ln) << 2), slotT + 256);
    }
}

// One bone-task: frame f, bone b (ja/jb/ob = f*150 + 3*joint, precomputed).
// Mask applied on read (pm = t!=0 ? p : 0; tm == t identically). The ob
// triple carries this task's share of the L1 term.
__device__ __forceinline__ void bone_task(const float* __restrict__ P,
                                          const float* __restrict__ T,
                                          int ja, int jb, int ob,
                                          float& l1, float& mse)
{
    float pax = P[ja], pay = P[ja + 1], paz = P[ja + 2];
    float pbx = P[jb], pby = P[jb + 1], pbz = P[jb + 2];
    float tax = T[ja], tay = T[ja + 1], taz = T[ja + 2];
    float tbx = T[jb], tby = T[jb + 1], tbz = T[jb + 2];
    float pox = P[ob], poy = P[ob + 1], poz = P[ob + 2];
    float tox = T[ob], toy = T[ob + 1], toz = T[ob + 2];

    pax = (tax != 0.0f) ? pax : 0.0f;
    pay = (tay != 0.0f) ? pay : 0.0f;
    paz = (taz != 0.0f) ? paz : 0.0f;
    pbx = (tbx != 0.0f) ? pbx : 0.0f;
    pby = (tby != 0.0f) ? pby : 0.0f;
    pbz = (tbz != 0.0f) ? pbz : 0.0f;
    pox = (tox != 0.0f) ? pox : 0.0f;
    poy = (toy != 0.0f) ? poy : 0.0f;
    poz = (toz != 0.0f) ? poz : 0.0f;

    l1 += fabsf(pox - tox) + fabsf(poy - toy) + fabsf(poz - toz);

    float dpx = pax - pbx, dpy = pay - pby, dpz = paz - pbz;
    float dtx = tax - tbx, dty = tay - tby, dtz = taz - tbz;
    float lp2 = dpx * dpx + dpy * dpy + dpz * dpz;
    float lt2 = dtx * dtx + dty * dty + dtz * dtz;
    // dir = diff * rsqrt(|diff|^2); exact 0 when diff == 0.
    // rsq approx err ~1e-7 vs 2.4e-2 tolerance (validated, absmax 0.0).
    float ip = (lp2 > 0.0f) ? __builtin_amdgcn_rsqf(lp2) : 0.0f;
    float it = (lt2 > 0.0f) ? __builtin_amdgcn_rsqf(lt2) : 0.0f;
    float e0 = dpx * ip - dtx * it;
    float e1 = dpy * ip - dty * it;
    float e2 = dpz * ip - dtz * it;
    mse += (tox != 0.0f) ? e0 * e0 : 0.0f;
    mse += (toy != 0.0f) ? e1 * e1 : 0.0f;
    mse += (toz != 0.0f) ? e2 * e2 : 0.0f;
}

__global__ __launch_bounds__(THREADS)
void loss_main(const float* __restrict__ preds,
               const float* __restrict__ targets,
               double* __restrict__ part0,
               double* __restrict__ part1)
{
    // Wave-PRIVATE 4-deep rings: no inter-wave LDS sharing, no barriers in
    // the main loop. Correctness rests only on each wave's own counted
    // vmcnt (asm w/ "memory" clobber = full compiler fence) and program
    // order (slot overwrite DMA is issued after its reads were consumed).
    // 4 waves x 4 slots x 2 tensors x 300 floats = 38400 B -> 4 blocks/CU.
    __shared__ float s_ring[WPB][DEPTH][2][TILE_F];

    const int tid = threadIdx.x;
    const int wv = tid >> 6;
    const int ln = tid & 63;
    const long long wid = (long long)blockIdx.x * WPB + wv;
    const long long tbase = wid * TPW;       // this wave's first tile

    // Task offsets, fixed per lane: task i = ln (+64), b = i>>1, f = i&1.
    int ja0, jb0, ob0, ja1, jb1, ob1;
    {
        int b = ln >> 1, f = ln & 1;         // task = ln, always < 100
        ja0 = f * FEAT + 3 * c_ba[b];
        jb0 = f * FEAT + 3 * c_bb[b];
        ob0 = f * FEAT + 3 * b;
        int i1 = 64 + ln;                    // valid iff ln < 36
        int ii = (i1 < NTASK) ? i1 : 0;
        b = ii >> 1; f = ii & 1;
        ja1 = f * FEAT + 3 * c_ba[b];
        jb1 = f * FEAT + 3 * c_bb[b];
        ob1 = f * FEAT + 3 * b;
    }

    float* wbase = &s_ring[wv][0][0][0];     // wave-uniform ring base

    float l1 = 0.0f, mse = 0.0f;

    // Prologue: fill slots 0..2 (12 vmcnt events for this wave).
#pragma unroll
    for (int s = 0; s < DEPTH - 1; ++s) {
        float* sp = wbase + s * (2 * TILE_F);
        stage_pair(preds, targets, sp, sp + TILE_F, ln, tbase + s);
    }

#pragma unroll 1
    for (int t = 0; t < TPW; ++t) {
        const int slot = t & (DEPTH - 1);
        // Steady state: issue tile t+3 into the slot this wave finished
        // reading at iter t-1 (program order + consumed values => the LDS
        // writes cannot precede those reads). Then wait ONLY for tile t:
        // 12 = the 3 newer tiles' events stay outstanding.
        if (t + DEPTH - 1 < TPW) {
            const int ns = (t + DEPTH - 1) & (DEPTH - 1);
            float* sp = wbase + ns * (2 * TILE_F);
            stage_pair(preds, targets, sp, sp + TILE_F, ln,
                       tbase + t + DEPTH - 1);
            asm volatile("s_waitcnt vmcnt(12)" ::: "memory");
        } else {
            const int rem = TPW - t;         // tiles still unconsumed (incl t)
            if (rem == 3)      asm volatile("s_waitcnt vmcnt(8)" ::: "memory");
            else if (rem == 2) asm volatile("s_waitcnt vmcnt(4)" ::: "memory");
            else               asm volatile("s_waitcnt vmcnt(0)" ::: "memory");
        }
        __builtin_amdgcn_sched_barrier(0);   // belt: keep reads below the wait

        const float* P = wbase + slot * (2 * TILE_F);
        const float* T = P + TILE_F;
        bone_task(P, T, ja0, jb0, ob0, l1, mse);
        if (ln < (NTASK - 64))
            bone_task(P, T, ja1, jb1, ob1, l1, mse);
        __builtin_amdgcn_sched_barrier(0);   // keep next DMA issue below reads
    }

    // ---- Block reduction (double); pipeline fully drained, plain sync ok ----
    double v0 = (double)l1;
    double v1 = (double)mse;
    for (int off = 32; off > 0; off >>= 1) {
        v0 += __shfl_down(v0, off, 64);
        v1 += __shfl_down(v1, off, 64);
    }
    __shared__ double s_red0[WPB];
    __shared__ double s_red1[WPB];
    if (ln == 0) { s_red0[wv] = v0; s_red1[wv] = v1; }
    __syncthreads();
    if (tid == 0) {
        part0[blockIdx.x] = s_red0[0] + s_red0[1] + s_red0[2] + s_red0[3];
        part1[blockIdx.x] = s_red1[0] + s_red1[1] + s_red1[2] + s_red1[3];
    }
}

__global__ __launch_bounds__(THREADS)
void loss_final(const double* __restrict__ part0,
                const double* __restrict__ part1,
                float* __restrict__ out)
{
    const int tid = threadIdx.x;
    double a = 0.0, b = 0.0;
    for (int i = tid; i < GRID_BLOCKS; i += THREADS) {
        a += part0[i];
        b += part1[i];
    }
    for (int off = 32; off > 0; off >>= 1) {
        a += __shfl_down(a, off, 64);
        b += __shfl_down(b, off, 64);
    }
    __shared__ double s0[THREADS / 64];
    __shared__ double s1[THREADS / 64];
    const int wave = tid >> 6;
    const int lane = tid & 63;
    if (lane == 0) { s0[wave] = a; s1[wave] = b; }
    __syncthreads();
    if (tid == 0) {
        double sa = s0[0] + s0[1] + s0[2] + s0[3];
        double sb = s1[0] + s1[1] + s1[2] + s1[3];
        const double N = 64.0 * 4096.0 * 150.0;  // both means over B*T*150
        out[0] = (float)(sa / N + 0.1 * (sb / N));
    }
}

extern "C" void kernel_launch(void* const* d_in, const int* in_sizes, int n_in,
                              void* d_out, int out_size, void* d_ws, size_t ws_size,
                              hipStream_t stream)
{
    (void)in_sizes; (void)n_in; (void)out_size; (void)ws_size;
    const float* preds   = (const float*)d_in[0];
    const float* targets = (const float*)d_in[1];
    double* part0 = (double*)d_ws;
    double* part1 = part0 + GRID_BLOCKS;   // 16 KB total in d_ws

    loss_main<<<GRID_BLOCKS, THREADS, 0, stream>>>(preds, targets, part0, part1);
    loss_final<<<1, THREADS, 0, stream>>>(part0, part1, (float*)d_out);
}